// Round 14
// baseline (617.811 us; speedup 1.0000x reference)
//
#include <hip/hip_runtime.h>
#include <hip/hip_bf16.h>

typedef unsigned short u16;
typedef unsigned int u32;
typedef _Float16 f16;
typedef __attribute__((ext_vector_type(8))) short bf16x8;
typedef __attribute__((ext_vector_type(8))) _Float16 f16x8;
typedef __attribute__((ext_vector_type(4))) float f32x4;
typedef __attribute__((ext_vector_type(4))) u16 u16x4;

__device__ __forceinline__ float bf2f(u16 u){ return __uint_as_float(((u32)u) << 16); }
__device__ __forceinline__ u16 f2bf(float f){
  u32 u = __float_as_uint(f);
  u += 0x7fffu + ((u >> 16) & 1u);
  return (u16)(u >> 16);
}
__device__ __forceinline__ void gll16(const u16* g, u16* l){
  __builtin_amdgcn_global_load_lds((const __attribute__((address_space(1))) u32*)g,
                                   (__attribute__((address_space(3))) u32*)l, 16, 0, 0);
}

#define MFMA16(a,b,c) __builtin_amdgcn_mfma_f32_16x16x32_bf16((a),(b),(c),0,0,0)
#define MFMAH(a,b,c)  __builtin_amdgcn_mfma_f32_16x16x32_f16((a),(b),(c),0,0,0)

// ---------------- merged preprocessing: fp32->fp16 inputs + 4x weight transpose (x256) ----------------
__global__ __launch_bounds__(256) void prep(const float* __restrict__ inq, const float* __restrict__ inkv,
                                            u16* __restrict__ oq, u16* __restrict__ okv,
                                            const float* __restrict__ w0, const float* __restrict__ w1,
                                            const float* __restrict__ w2, const float* __restrict__ w3,
                                            u16* __restrict__ o0, u16* __restrict__ o1,
                                            u16* __restrict__ o2, u16* __restrict__ o3){
  __shared__ float tile[64*68];
  const int bid = blockIdx.x;
  const int t = threadIdx.x;
  if (bid < 16384){
    const int half = bid >> 13;
    const float* in = half ? inkv : inq;
    u16* out = half ? okv : oq;
    const size_t i = ((size_t)(bid & 8191)*256 + t)*8;
    f16 h[8];
    #pragma unroll
    for (int j=0;j<8;j++) h[j] = (f16)in[i+j];
    *(f16x8*)(out+i) = *(f16x8*)h;
    return;
  }
  const int r = bid - 16384;
  const int z = r >> 10, b2 = r & 1023;
  const float* in = (z==0) ? w0 : (z==1) ? w1 : (z==2) ? w2 : w3;
  u16* oh = (z==0) ? o0 : (z==1) ? o1 : (z==2) ? o2 : o3;
  const int r0 = (b2 >> 5)*64, c0 = (b2 & 31)*64;
  #pragma unroll
  for (int p=0;p<2;p++){
    const int row = p*32 + (t>>3), cg = (t&7)*8;
    const float* s = in + (size_t)(r0+row)*2048 + c0 + cg;
    #pragma unroll
    for (int j=0;j<8;j++) tile[row*68 + cg + j] = s[j];
  }
  __syncthreads();
  #pragma unroll
  for (int p=0;p<2;p++){
    const int orow = p*32 + (t>>3), cg = (t&7)*8;
    f16 h[8];
    #pragma unroll
    for (int j=0;j<8;j++) h[j] = (f16)(tile[(cg+j)*68 + orow] * 256.f);
    *(f16x8*)(oh + (size_t)(c0+orow)*2048 + r0 + cg) = *(f16x8*)h;
  }
}

// ================= 8-phase 256x256 fp16 GEMM (T2+T3+T4+T5), M=8192 N=K=2048 =================
template<int EPI>
__global__ __launch_bounds__(512, 1) void gemm8(const u16* __restrict__ A,
                                                const u16* __restrict__ Bt,
                                                const float* __restrict__ scale,
                                                u16* __restrict__ C,
                                                float* __restrict__ Cf){
  constexpr int K = 2048, NT = 32;
  __shared__ __align__(16) u16 AL[2][2][8192];
  __shared__ __align__(16) u16 BL[2][2][8192];
  __shared__ float red[2][4][128];

  const int t = threadIdx.x;
  const int lane = t & 63, w = t >> 6;
  const int wm = w >> 2, wn = w & 3;
  const int l15 = lane & 15, l4 = lane >> 4;

  const int bid = blockIdx.x;
  const int xcd = bid & 7, q = bid >> 3;
  const int m0 = (((xcd >> 1) << 3) + (q >> 2)) * 256;
  const int n0 = (((xcd & 1) << 2) + (q & 3)) * 256;

  const int srow = t >> 2;
  const int skg = (t & 3) ^ ((srow ^ (srow >> 2)) & 3);
  const u16* gA = A  + (size_t)(m0 + srow) * K + skg * 8;
  const u16* gB = Bt + (size_t)(n0 + srow) * K + skg * 8;
  const int d0 = (w * 64) * 8;
  const int d1 = (512 + w * 64) * 8;

  const int sz = (l15 ^ (l15 >> 2)) & 3;
  const int kgp = ((l4 ^ sz) & 3) * 8;
  const int aoff = (wm * 128 + l15) * 32 + kgp;
  const int boff = (wn * 64 + l15) * 32 + kgp;

  f32x4 acc[8][4] = {};

#define STG_A(tile, kh, db) { const u16* s_ = gA + (size_t)(tile)*64 + (kh)*32; \
    gll16(s_, &AL[db][kh][0] + d0); gll16(s_ + (size_t)128*K, &AL[db][kh][0] + d1); }
#define STG_B(tile, kh, db) { const u16* s_ = gB + (size_t)(tile)*64 + (kh)*32; \
    gll16(s_, &BL[db][kh][0] + d0); gll16(s_ + (size_t)128*K, &BL[db][kh][0] + d1); }

  STG_A(0,0,0); STG_B(0,0,0);
  STG_A(0,1,0); STG_B(0,1,0);
  STG_A(1,0,1); STG_B(1,0,1);
  asm volatile("s_waitcnt vmcnt(4)" ::: "memory");
  __builtin_amdgcn_s_barrier();

  for (int g = 0; g < NT; ++g){
    const int db = g & 1, db1 = db ^ 1;
    const int t1 = (g+1 < NT) ? g+1 : NT-1;
    const int t2 = (g+2 < NT) ? g+2 : NT-1;
    f16x8 a[4], b[4];

    #pragma unroll
    for (int nf=0; nf<4; nf++) b[nf] = *(const f16x8*)&BL[db][0][boff + nf*512];
    #pragma unroll
    for (int mf=0; mf<4; mf++) a[mf] = *(const f16x8*)&AL[db][0][aoff + mf*512];
    STG_A(t1, 1, db1);
    __builtin_amdgcn_s_barrier();
    asm volatile("s_waitcnt lgkmcnt(0)" ::: "memory");
    __builtin_amdgcn_sched_barrier(0);
    __builtin_amdgcn_s_setprio(1);
    #pragma unroll
    for (int mf=0; mf<4; mf++)
      #pragma unroll
      for (int nf=0; nf<4; nf++)
        acc[mf][nf] = MFMAH(a[mf], b[nf], acc[mf][nf]);
    __builtin_amdgcn_s_setprio(0);
    __builtin_amdgcn_s_barrier();

    #pragma unroll
    for (int mf=0; mf<4; mf++) a[mf] = *(const f16x8*)&AL[db][0][aoff + (mf+4)*512];
    STG_B(t1, 1, db1);
    __builtin_amdgcn_s_barrier();
    asm volatile("s_waitcnt lgkmcnt(0)" ::: "memory");
    __builtin_amdgcn_sched_barrier(0);
    __builtin_amdgcn_s_setprio(1);
    #pragma unroll
    for (int mf=0; mf<4; mf++)
      #pragma unroll
      for (int nf=0; nf<4; nf++)
        acc[mf+4][nf] = MFMAH(a[mf], b[nf], acc[mf+4][nf]);
    __builtin_amdgcn_s_setprio(0);
    __builtin_amdgcn_s_barrier();

    #pragma unroll
    for (int nf=0; nf<4; nf++) b[nf] = *(const f16x8*)&BL[db][1][boff + nf*512];
    #pragma unroll
    for (int mf=0; mf<4; mf++) a[mf] = *(const f16x8*)&AL[db][1][aoff + mf*512];
    STG_A(t2, 0, db);
    __builtin_amdgcn_s_barrier();
    asm volatile("s_waitcnt lgkmcnt(0)" ::: "memory");
    __builtin_amdgcn_sched_barrier(0);
    __builtin_amdgcn_s_setprio(1);
    #pragma unroll
    for (int mf=0; mf<4; mf++)
      #pragma unroll
      for (int nf=0; nf<4; nf++)
        acc[mf][nf] = MFMAH(a[mf], b[nf], acc[mf][nf]);
    __builtin_amdgcn_s_setprio(0);
    __builtin_amdgcn_s_barrier();

    #pragma unroll
    for (int mf=0; mf<4; mf++) a[mf] = *(const f16x8*)&AL[db][1][aoff + (mf+4)*512];
    STG_B(t2, 0, db);
    __builtin_amdgcn_s_barrier();
    asm volatile("s_waitcnt lgkmcnt(0)" ::: "memory");
    __builtin_amdgcn_sched_barrier(0);
    __builtin_amdgcn_s_setprio(1);
    #pragma unroll
    for (int mf=0; mf<4; mf++)
      #pragma unroll
      for (int nf=0; nf<4; nf++)
        acc[mf+4][nf] = MFMAH(a[mf], b[nf], acc[mf+4][nf]);
    __builtin_amdgcn_s_setprio(0);
    asm volatile("s_waitcnt vmcnt(4)" ::: "memory");
    __builtin_amdgcn_s_barrier();
  }

  asm volatile("s_waitcnt vmcnt(0)" ::: "memory");
  __builtin_amdgcn_s_barrier();

  const float us = 1.f/256.f;
  if (EPI == 0){
    #pragma unroll
    for (int mf=0; mf<8; mf++)
      #pragma unroll
      for (int nf=0; nf<4; nf++)
        #pragma unroll
        for (int r=0;r<4;r++) acc[mf][nf][r] *= us;
    #pragma unroll
    for (int mf=0; mf<8; mf++){
      #pragma unroll
      for (int r=0;r<4;r++){
        float p = acc[mf][0][r]*acc[mf][0][r] + acc[mf][1][r]*acc[mf][1][r]
                + acc[mf][2][r]*acc[mf][2][r] + acc[mf][3][r]*acc[mf][3][r];
        #pragma unroll
        for (int d=1; d<16; d<<=1) p += __shfl_xor(p, d, 64);
        if (l15 == 0) red[wm][wn][mf*16 + l4*4 + r] = p;
      }
    }
    __syncthreads();
    float sc[4];
    #pragma unroll
    for (int nf=0; nf<4; nf++) sc[nf] = scale[(wn*64 + nf*16 + l15) & 127];
    #pragma unroll
    for (int mf=0; mf<8; mf++){
      #pragma unroll
      for (int r=0;r<4;r++){
        const int rl = mf*16 + l4*4 + r;
        const float inv = rsqrtf((red[wm][wn & 2][rl] + red[wm][(wn & 2) | 1][rl])*(1.f/128.f) + 1e-6f);
        const size_t grow = (size_t)(m0 + wm*128 + rl);
        #pragma unroll
        for (int nf=0; nf<4; nf++){
          f16 hv = (f16)(acc[mf][nf][r]*inv*sc[nf]);
          C[grow*2048 + (n0 + wn*64 + nf*16 + l15)] = *reinterpret_cast<u16*>(&hv);
        }
      }
    }
  } else if (EPI == 1){
    #pragma unroll
    for (int mf=0; mf<8; mf++){
      const int m = m0 + wm*128 + mf*16 + l4*4;
      const int bb = m >> 11, s = m & 2047;
      #pragma unroll
      for (int nf=0; nf<4; nf++){
        const int n = n0 + wn*64 + nf*16 + l15;
        u16x4 pk;
        pk.x = f2bf(acc[mf][nf][0]*us); pk.y = f2bf(acc[mf][nf][1]*us);
        pk.z = f2bf(acc[mf][nf][2]*us); pk.w = f2bf(acc[mf][nf][3]*us);
        *(u16x4*)&C[((size_t)(bb*16 + (n>>7))*128 + (n&127))*2048 + s] = pk;
      }
    }
  } else {
    #pragma unroll
    for (int mf=0; mf<8; mf++){
      const size_t r0 = (size_t)(m0 + wm*128 + mf*16 + l4*4);
      #pragma unroll
      for (int nf=0; nf<4; nf++){
        const int c = n0 + wn*64 + nf*16 + l15;
        #pragma unroll
        for (int r=0;r<4;r++)
          Cf[(r0+r)*2048 + c] = acc[mf][nf][r]*us;
      }
    }
  }
#undef STG_A
#undef STG_B
}

// ---------------- Flash attention: K dbuf counted-vmcnt pipeline; V direct from L2 ----------------
// Q,K fp16 in [B,S,H,Dh]; V bf16 in [B,H,Dh,S]; out ctx fp16 [B,S,H,Dh]
// V tile per (b,h) is L2-resident (XCD chunking) -> PV B-frags load straight from global
// (one 128B line per V-row per tile), removing Vsh staging + 16 ds_read_b128/wave/tile.
__global__ __launch_bounds__(256, 2) void attn_fwd(const u16* __restrict__ Qh_,
                                                   const u16* __restrict__ Kh_,
                                                   const u16* __restrict__ Vt, u16* __restrict__ O){
  __shared__ __align__(16) u16 Ksh[2][64*128];   // fp16 dbuf, granule-swizzled content
  __shared__ __align__(16) u16 Psh[4][32*72];    // bf16 per-wave P
  const int t = threadIdx.x;
  const int lane = t & 63, w = t >> 6;
  const int l15 = lane & 15, l4 = lane >> 4;
  const int lin = blockIdx.x;
  const int bh  = (lin & 7)*8 + (lin >> 7);
  const int qt  = (lin >> 3) & 15;
  const int b = bh >> 4, h = bh & 15;
  const int q0 = qt*128 + w*32;

  f16x8 qh[2][4];
  #pragma unroll
  for (int qf=0;qf<2;qf++){
    const size_t qoff = ((size_t)((b<<11) + q0 + qf*16 + l15)*16 + h)*128 + l4*8;
    #pragma unroll
    for (int kk=0;kk<4;kk++)
      qh[qf][kk] = *(const f16x8*)(Qh_ + qoff + kk*32);
  }
  f32x4 oacc[2][8] = {};
  float lpart[2][4] = {};

  size_t ksrc[4];
  #pragma unroll
  for (int p=0;p<4;p++){
    const int g = p*256 + t;
    ksrc[p] = ((size_t)((b<<11) + (g>>4))*16 + h)*128 + (size_t)((((g&15) ^ ((g>>4)&7))*8));
  }
  // per-lane V base: row = n*16 + l15, col = tt*64 + ks2*32 + l4*8
  const u16* vg = Vt + (size_t)(b*16 + h)*262144 + (size_t)l15*2048 + l4*8;

#define STK(T, DB) { const size_t ko_ = (size_t)(T)*131072; \
    _Pragma("unroll") for (int p_=0;p_<4;p_++) gll16(Kh_ + ksrc[p_] + ko_, &Ksh[DB][0] + (p_*256+t)*8); }

  // prologue: K0, K1 in flight; wait K0 (leave K1's 4)
  STK(0,0); STK(1,1);
  asm volatile("s_waitcnt vmcnt(4)" ::: "memory");
  __builtin_amdgcn_s_barrier();

  for (int tt = 0; tt < 32; ++tt){
    const int c = tt & 1;

    // QK^T from Ksh[c]
    f32x4 sa[2][4] = {};
    #pragma unroll
    for (int ks=0;ks<4;ks++){
      const int row = ks*16 + l15;
      #pragma unroll
      for (int kk=0;kk<4;kk++){
        const int off = row*128 + (((kk*4 + l4) ^ (row&7))*8);
        f16x8 khf = *(const f16x8*)&Ksh[c][off];
        sa[0][ks] = MFMAH(qh[0][kk], khf, sa[0][ks]);
        sa[1][ks] = MFMAH(qh[1][kk], khf, sa[1][ks]);
      }
    }
    // V chunk0 (ks2=0): 8 direct loads; latency hides under softmax
    bf16x8 vb0[8];
    #pragma unroll
    for (int n=0;n<8;n++) vb0[n] = *(const bf16x8*)(vg + (size_t)n*32768 + tt*64);

    // static-offset softmax: P = exp(s - 24)
    #pragma unroll
    for (int qf=0;qf<2;qf++)
      #pragma unroll
      for (int r=0;r<4;r++){
        float rs = 0.f;
        #pragma unroll
        for (int ks=0;ks<4;ks++){
          const float e = __expf(sa[qf][ks][r] - 24.f);
          rs += e;
          Psh[w][(qf*16 + l4*4 + r)*72 + ks*16 + l15] = f2bf(e);
        }
        lpart[qf][r] += rs;
      }
    asm volatile("s_waitcnt lgkmcnt(0)" ::: "memory");
    __builtin_amdgcn_sched_barrier(0);
    __builtin_amdgcn_s_barrier();          // B1: all waves done reading Ksh[c]

    // V chunk1 BEFORE STK so its use-wait leaves the K prefetch in flight
    bf16x8 vb1[8];
    #pragma unroll
    for (int n=0;n<8;n++) vb1[n] = *(const bf16x8*)(vg + (size_t)n*32768 + tt*64 + 32);
    const int tk = (tt+2 < 32) ? tt+2 : 31;
    STK(tk, c);                            // restage over Ksh[c]

    // PV: ks2=0 with vb0, ks2=1 with vb1
    {
      bf16x8 pa0 = *(const bf16x8*)&Psh[w][l15*72 + l4*8];
      bf16x8 pa1 = *(const bf16x8*)&Psh[w][(16 + l15)*72 + l4*8];
      #pragma unroll
      for (int n=0;n<8;n++){
        oacc[0][n] = MFMA16(pa0, vb0[n], oacc[0][n]);
        oacc[1][n] = MFMA16(pa1, vb0[n], oacc[1][n]);
      }
      bf16x8 pb0 = *(const bf16x8*)&Psh[w][l15*72 + 32 + l4*8];
      bf16x8 pb1 = *(const bf16x8*)&Psh[w][(16 + l15)*72 + 32 + l4*8];
      #pragma unroll
      for (int n=0;n<8;n++){
        oacc[0][n] = MFMA16(pb0, vb1[n], oacc[0][n]);
        oacc[1][n] = MFMA16(pb1, vb1[n], oacc[1][n]);
      }
    }
    asm volatile("s_waitcnt vmcnt(4)" ::: "memory");   // K[tt+1] complete (STK(tt+2) in flight)
    __builtin_amdgcn_s_barrier();          // B2: K[tt+1] visible for next QK
  }
  asm volatile("s_waitcnt vmcnt(0)" ::: "memory");

#undef STK

  #pragma unroll
  for (int qf=0;qf<2;qf++){
    float lrun[4];
    #pragma unroll
    for (int r=0;r<4;r++){
      float s = lpart[qf][r];
      #pragma unroll
      for (int d=1; d<16; d<<=1) s += __shfl_xor(s, d, 64);
      lrun[r] = s;
    }
    #pragma unroll
    for (int n=0;n<8;n++){
      const int d = n*16 + l15;
      #pragma unroll
      for (int r=0;r<4;r++){
        const int s = q0 + qf*16 + l4*4 + r;
        f16 hv = (f16)(oacc[qf][n][r] / lrun[r]);
        O[((size_t)((b<<11) + s)*16 + h)*128 + d] = *reinterpret_cast<u16*>(&hv);
      }
    }
  }
}

extern "C" void kernel_launch(void* const* d_in, const int* in_sizes, int n_in,
                              void* d_out, int out_size, void* d_ws, size_t ws_size,
                              hipStream_t stream){
  const float* f_inq = (const float*)d_in[0];
  const float* f_inkv= (const float*)d_in[1];
  const float* f_Wq  = (const float*)d_in[2];
  const float* f_Wk  = (const float*)d_in[3];
  const float* f_Wv  = (const float*)d_in[4];
  const float* scq   = (const float*)d_in[5];
  const float* sck   = (const float*)d_in[6];
  const float* f_Wo  = (const float*)d_in[7];

  u16* ws = (u16*)d_ws;
  const size_t ACT = (size_t)16777216;   // 4*2048*16*128
  const size_t WEL = (size_t)4194304;    // 2048*2048
  u16* q_h = ws;               // fp16
  u16* k_h = q_h + ACT;        // fp16
  u16* v_t = k_h + ACT;        // bf16 [B,H,Dh,S]
  u16* ctx = v_t + ACT;        // fp16
  u16* wq  = ctx + ACT;        // fp16 weights, x256
  u16* wk  = wq + WEL;
  u16* wv  = wk + WEL;
  u16* wo  = wv + WEL;

  u16* inq16  = (u16*)d_out;   // fp16 input staging in d_out, consumed before final GEMM
  u16* inkv16 = inq16 + ACT;

  prep<<<20480, 256, 0, stream>>>(f_inq, f_inkv, inq16, inkv16,
                                  f_Wq, f_Wk, f_Wv, f_Wo, wq, wk, wv, wo);

  gemm8<0><<<256, 512, 0, stream>>>(inq16,  wq, scq, q_h, nullptr);
  gemm8<0><<<256, 512, 0, stream>>>(inkv16, wk, sck, k_h, nullptr);
  gemm8<1><<<256, 512, 0, stream>>>(inkv16, wv, nullptr, v_t, nullptr);

  attn_fwd<<<dim3(1024), 256, 0, stream>>>(q_h, k_h, v_t, ctx);

  gemm8<2><<<256, 512, 0, stream>>>(ctx, wo, nullptr, nullptr, (float*)d_out);
}

// Round 15
// 512.119 us; speedup vs baseline: 1.2064x; 1.2064x over previous
//
#include <hip/hip_runtime.h>
#include <hip/hip_bf16.h>

typedef unsigned short u16;
typedef unsigned int u32;
typedef _Float16 f16;
typedef __attribute__((ext_vector_type(8))) short bf16x8;
typedef __attribute__((ext_vector_type(8))) _Float16 f16x8;
typedef __attribute__((ext_vector_type(4))) float f32x4;
typedef __attribute__((ext_vector_type(4))) u16 u16x4;

__device__ __forceinline__ float bf2f(u16 u){ return __uint_as_float(((u32)u) << 16); }
__device__ __forceinline__ u16 f2bf(float f){
  u32 u = __float_as_uint(f);
  u += 0x7fffu + ((u >> 16) & 1u);
  return (u16)(u >> 16);
}
__device__ __forceinline__ void gll16(const u16* g, u16* l){
  __builtin_amdgcn_global_load_lds((const __attribute__((address_space(1))) u32*)g,
                                   (__attribute__((address_space(3))) u32*)l, 16, 0, 0);
}

#define MFMA16(a,b,c) __builtin_amdgcn_mfma_f32_16x16x32_bf16((a),(b),(c),0,0,0)
#define MFMAH(a,b,c)  __builtin_amdgcn_mfma_f32_16x16x32_f16((a),(b),(c),0,0,0)

// ---------------- merged preprocessing: fp32->fp16 inputs + 4x weight transpose (x256) ----------------
__global__ __launch_bounds__(256) void prep(const float* __restrict__ inq, const float* __restrict__ inkv,
                                            u16* __restrict__ oq, u16* __restrict__ okv,
                                            const float* __restrict__ w0, const float* __restrict__ w1,
                                            const float* __restrict__ w2, const float* __restrict__ w3,
                                            u16* __restrict__ o0, u16* __restrict__ o1,
                                            u16* __restrict__ o2, u16* __restrict__ o3){
  __shared__ float tile[64*68];
  const int bid = blockIdx.x;
  const int t = threadIdx.x;
  if (bid < 16384){
    const int half = bid >> 13;
    const float* in = half ? inkv : inq;
    u16* out = half ? okv : oq;
    const size_t i = ((size_t)(bid & 8191)*256 + t)*8;
    f16 h[8];
    #pragma unroll
    for (int j=0;j<8;j++) h[j] = (f16)in[i+j];
    *(f16x8*)(out+i) = *(f16x8*)h;
    return;
  }
  const int r = bid - 16384;
  const int z = r >> 10, b2 = r & 1023;
  const float* in = (z==0) ? w0 : (z==1) ? w1 : (z==2) ? w2 : w3;
  u16* oh = (z==0) ? o0 : (z==1) ? o1 : (z==2) ? o2 : o3;
  const int r0 = (b2 >> 5)*64, c0 = (b2 & 31)*64;
  #pragma unroll
  for (int p=0;p<2;p++){
    const int row = p*32 + (t>>3), cg = (t&7)*8;
    const float* s = in + (size_t)(r0+row)*2048 + c0 + cg;
    #pragma unroll
    for (int j=0;j<8;j++) tile[row*68 + cg + j] = s[j];
  }
  __syncthreads();
  #pragma unroll
  for (int p=0;p<2;p++){
    const int orow = p*32 + (t>>3), cg = (t&7)*8;
    f16 h[8];
    #pragma unroll
    for (int j=0;j<8;j++) h[j] = (f16)(tile[(cg+j)*68 + orow] * 256.f);
    *(f16x8*)(oh + (size_t)(c0+orow)*2048 + r0 + cg) = *(f16x8*)h;
  }
}

// ============ 8-phase 256x256 fp16 GEMM main loop (shared macro body) ============
#define GEMM8_MAIN_LOOP(A_, B_)                                                     \
  const int srow = t >> 2;                                                          \
  const int skg = (t & 3) ^ ((srow ^ (srow >> 2)) & 3);                             \
  const u16* gA = A_ + (size_t)(m0 + srow) * 2048 + skg * 8;                        \
  const u16* gB = B_ + (size_t)(n0 + srow) * 2048 + skg * 8;                        \
  const int d0 = (w * 64) * 8;                                                      \
  const int d1 = (512 + w * 64) * 8;                                                \
  const int sz = (l15 ^ (l15 >> 2)) & 3;                                            \
  const int kgp = ((l4 ^ sz) & 3) * 8;                                              \
  const int aoff = (wm * 128 + l15) * 32 + kgp;                                     \
  const int boff = (wn * 64 + l15) * 32 + kgp;                                      \
  STG_A(0,0,0); STG_B(0,0,0);                                                       \
  STG_A(0,1,0); STG_B(0,1,0);                                                       \
  STG_A(1,0,1); STG_B(1,0,1);                                                       \
  asm volatile("s_waitcnt vmcnt(4)" ::: "memory");                                  \
  __builtin_amdgcn_s_barrier();                                                     \
  for (int g = 0; g < 32; ++g){                                                     \
    const int db = g & 1, db1 = db ^ 1;                                             \
    const int t1 = (g+1 < 32) ? g+1 : 31;                                           \
    const int t2 = (g+2 < 32) ? g+2 : 31;                                           \
    f16x8 a[4], b[4];                                                               \
    _Pragma("unroll")                                                               \
    for (int nf=0; nf<4; nf++) b[nf] = *(const f16x8*)&AL[2+db][0][boff + nf*512];  \
    _Pragma("unroll")                                                               \
    for (int mf=0; mf<4; mf++) a[mf] = *(const f16x8*)&AL[db][0][aoff + mf*512];    \
    STG_A(t1, 1, db1);                                                              \
    __builtin_amdgcn_s_barrier();                                                   \
    asm volatile("s_waitcnt lgkmcnt(0)" ::: "memory");                              \
    __builtin_amdgcn_sched_barrier(0);                                              \
    __builtin_amdgcn_s_setprio(1);                                                  \
    _Pragma("unroll")                                                               \
    for (int mf=0; mf<4; mf++)                                                      \
      _Pragma("unroll")                                                             \
      for (int nf=0; nf<4; nf++)                                                    \
        acc[mf][nf] = MFMAH(a[mf], b[nf], acc[mf][nf]);                             \
    __builtin_amdgcn_s_setprio(0);                                                  \
    __builtin_amdgcn_s_barrier();                                                   \
    _Pragma("unroll")                                                               \
    for (int mf=0; mf<4; mf++) a[mf] = *(const f16x8*)&AL[db][0][aoff + (mf+4)*512];\
    STG_B(t1, 1, db1);                                                              \
    __builtin_amdgcn_s_barrier();                                                   \
    asm volatile("s_waitcnt lgkmcnt(0)" ::: "memory");                              \
    __builtin_amdgcn_sched_barrier(0);                                              \
    __builtin_amdgcn_s_setprio(1);                                                  \
    _Pragma("unroll")                                                               \
    for (int mf=0; mf<4; mf++)                                                      \
      _Pragma("unroll")                                                             \
      for (int nf=0; nf<4; nf++)                                                    \
        acc[mf+4][nf] = MFMAH(a[mf], b[nf], acc[mf+4][nf]);                         \
    __builtin_amdgcn_s_setprio(0);                                                  \
    __builtin_amdgcn_s_barrier();                                                   \
    _Pragma("unroll")                                                               \
    for (int nf=0; nf<4; nf++) b[nf] = *(const f16x8*)&AL[2+db][1][boff + nf*512];  \
    _Pragma("unroll")                                                               \
    for (int mf=0; mf<4; mf++) a[mf] = *(const f16x8*)&AL[db][1][aoff + mf*512];    \
    STG_A(t2, 0, db);                                                               \
    __builtin_amdgcn_s_barrier();                                                   \
    asm volatile("s_waitcnt lgkmcnt(0)" ::: "memory");                              \
    __builtin_amdgcn_sched_barrier(0);                                              \
    __builtin_amdgcn_s_setprio(1);                                                  \
    _Pragma("unroll")                                                               \
    for (int mf=0; mf<4; mf++)                                                      \
      _Pragma("unroll")                                                             \
      for (int nf=0; nf<4; nf++)                                                    \
        acc[mf][nf] = MFMAH(a[mf], b[nf], acc[mf][nf]);                             \
    __builtin_amdgcn_s_setprio(0);                                                  \
    __builtin_amdgcn_s_barrier();                                                   \
    _Pragma("unroll")                                                               \
    for (int mf=0; mf<4; mf++) a[mf] = *(const f16x8*)&AL[db][1][aoff + (mf+4)*512];\
    STG_B(t2, 0, db);                                                               \
    __builtin_amdgcn_s_barrier();                                                   \
    asm volatile("s_waitcnt lgkmcnt(0)" ::: "memory");                              \
    __builtin_amdgcn_sched_barrier(0);                                              \
    __builtin_amdgcn_s_setprio(1);                                                  \
    _Pragma("unroll")                                                               \
    for (int mf=0; mf<4; mf++)                                                      \
      _Pragma("unroll")                                                             \
      for (int nf=0; nf<4; nf++)                                                    \
        acc[mf+4][nf] = MFMAH(a[mf], b[nf], acc[mf+4][nf]);                         \
    __builtin_amdgcn_s_setprio(0);                                                  \
    asm volatile("s_waitcnt vmcnt(4)" ::: "memory");                                \
    __builtin_amdgcn_s_barrier();                                                   \
  }                                                                                 \
  asm volatile("s_waitcnt vmcnt(0)" ::: "memory");                                  \
  __builtin_amdgcn_s_barrier();

#define STG_A(tile, kh, db) { const u16* s_ = gA + (size_t)(tile)*64 + (kh)*32; \
    gll16(s_, &AL[db][kh][0] + d0); gll16(s_ + (size_t)128*2048, &AL[db][kh][0] + d1); }
#define STG_B(tile, kh, db) { const u16* s_ = gB + (size_t)(tile)*64 + (kh)*32; \
    gll16(s_, &AL[2+db][kh][0] + d0); gll16(s_ + (size_t)128*2048, &AL[2+db][kh][0] + d1); }

// -------- fused q/k/v projection GEMMs: z selects operands; epilogue RMSNorm(fp16) or V-transpose(bf16) --------
__global__ __launch_bounds__(512, 1) void gemm8_qkv(const u16* __restrict__ inq, const u16* __restrict__ inkv,
                                                    const u16* __restrict__ wq, const u16* __restrict__ wk,
                                                    const u16* __restrict__ wv,
                                                    const float* __restrict__ scq, const float* __restrict__ sck,
                                                    u16* __restrict__ q_h, u16* __restrict__ k_h,
                                                    u16* __restrict__ v_t){
  __shared__ __align__(16) u16 AL[4][2][8192];   // [0,1]=A dbuf, [2,3]=B dbuf
  __shared__ float red[2][4][128];

  const int t = threadIdx.x;
  const int lane = t & 63, w = t >> 6;
  const int wm = w >> 2, wn = w & 3;
  const int l15 = lane & 15, l4 = lane >> 4;

  const int z = blockIdx.x >> 8;
  const int bid = blockIdx.x & 255;
  const int xcd = bid & 7, q = bid >> 3;
  const int m0 = (((xcd >> 1) << 3) + (q >> 2)) * 256;
  const int n0 = (((xcd & 1) << 2) + (q & 3)) * 256;

  const u16* A  = (z==0) ? inq : inkv;
  const u16* Bt = (z==0) ? wq : (z==1) ? wk : wv;
  const float* scale = (z==0) ? scq : sck;

  f32x4 acc[8][4] = {};
  GEMM8_MAIN_LOOP(A, Bt)

  const float us = 1.f/256.f;
  if (z < 2){
    u16* C = (z==0) ? q_h : k_h;
    #pragma unroll
    for (int mf=0; mf<8; mf++)
      #pragma unroll
      for (int nf=0; nf<4; nf++)
        #pragma unroll
        for (int r=0;r<4;r++) acc[mf][nf][r] *= us;
    #pragma unroll
    for (int mf=0; mf<8; mf++){
      #pragma unroll
      for (int r=0;r<4;r++){
        float p = acc[mf][0][r]*acc[mf][0][r] + acc[mf][1][r]*acc[mf][1][r]
                + acc[mf][2][r]*acc[mf][2][r] + acc[mf][3][r]*acc[mf][3][r];
        #pragma unroll
        for (int d=1; d<16; d<<=1) p += __shfl_xor(p, d, 64);
        if (l15 == 0) red[wm][wn][mf*16 + l4*4 + r] = p;
      }
    }
    __syncthreads();
    float sc[4];
    #pragma unroll
    for (int nf=0; nf<4; nf++) sc[nf] = scale[(wn*64 + nf*16 + l15) & 127];
    #pragma unroll
    for (int mf=0; mf<8; mf++){
      #pragma unroll
      for (int r=0;r<4;r++){
        const int rl = mf*16 + l4*4 + r;
        const float inv = rsqrtf((red[wm][wn & 2][rl] + red[wm][(wn & 2) | 1][rl])*(1.f/128.f) + 1e-6f);
        const size_t grow = (size_t)(m0 + wm*128 + rl);
        #pragma unroll
        for (int nf=0; nf<4; nf++){
          f16 hv = (f16)(acc[mf][nf][r]*inv*sc[nf]);
          C[grow*2048 + (n0 + wn*64 + nf*16 + l15)] = *reinterpret_cast<u16*>(&hv);
        }
      }
    }
  } else {
    #pragma unroll
    for (int mf=0; mf<8; mf++){
      const int m = m0 + wm*128 + mf*16 + l4*4;
      const int bb = m >> 11, s = m & 2047;
      #pragma unroll
      for (int nf=0; nf<4; nf++){
        const int n = n0 + wn*64 + nf*16 + l15;
        u16x4 pk;
        pk.x = f2bf(acc[mf][nf][0]*us); pk.y = f2bf(acc[mf][nf][1]*us);
        pk.z = f2bf(acc[mf][nf][2]*us); pk.w = f2bf(acc[mf][nf][3]*us);
        *(u16x4*)&v_t[((size_t)(bb*16 + (n>>7))*128 + (n&127))*2048 + s] = pk;
      }
    }
  }
}

// -------- final GEMM: ctx x Wo -> fp32 out --------
__global__ __launch_bounds__(512, 1) void gemm8_out(const u16* __restrict__ A,
                                                    const u16* __restrict__ Bt,
                                                    float* __restrict__ Cf){
  __shared__ __align__(16) u16 AL[4][2][8192];
  const int t = threadIdx.x;
  const int lane = t & 63, w = t >> 6;
  const int wm = w >> 2, wn = w & 3;
  const int l15 = lane & 15, l4 = lane >> 4;

  const int bid = blockIdx.x;
  const int xcd = bid & 7, q = bid >> 3;
  const int m0 = (((xcd >> 1) << 3) + (q >> 2)) * 256;
  const int n0 = (((xcd & 1) << 2) + (q & 3)) * 256;

  f32x4 acc[8][4] = {};
  GEMM8_MAIN_LOOP(A, Bt)

  const float us = 1.f/256.f;
  #pragma unroll
  for (int mf=0; mf<8; mf++){
    const size_t r0 = (size_t)(m0 + wm*128 + mf*16 + l4*4);
    #pragma unroll
    for (int nf=0; nf<4; nf++){
      const int c = n0 + wn*64 + nf*16 + l15;
      #pragma unroll
      for (int r=0;r<4;r++)
        Cf[(r0+r)*2048 + c] = acc[mf][nf][r]*us;
    }
  }
}

// ---------------- Flash attention: counted-vmcnt pipeline (r11 verbatim, 190us verified) ----------------
__global__ __launch_bounds__(256, 2) void attn_fwd(const u16* __restrict__ Qh_,
                                                   const u16* __restrict__ Kh_,
                                                   const u16* __restrict__ Vt, u16* __restrict__ O){
  __shared__ __align__(16) u16 Ksh[2][64*128];   // fp16 dbuf, granule-swizzled content
  __shared__ __align__(16) u16 Vsh[128*64];      // bf16 single buffer
  __shared__ __align__(16) u16 Psh[4][32*72];    // bf16 per-wave P
  const int t = threadIdx.x;
  const int lane = t & 63, w = t >> 6;
  const int l15 = lane & 15, l4 = lane >> 4;
  const int lin = blockIdx.x;
  const int bh  = (lin & 7)*8 + (lin >> 7);
  const int qt  = (lin >> 3) & 15;
  const int b = bh >> 4, h = bh & 15;
  const int q0 = qt*128 + w*32;

  f16x8 qh[2][4];
  #pragma unroll
  for (int qf=0;qf<2;qf++){
    const size_t qoff = ((size_t)((b<<11) + q0 + qf*16 + l15)*16 + h)*128 + l4*8;
    #pragma unroll
    for (int kk=0;kk<4;kk++)
      qh[qf][kk] = *(const f16x8*)(Qh_ + qoff + kk*32);
  }
  f32x4 oacc[2][8] = {};
  float lpart[2][4] = {};

  size_t ksrc[4], vsrc[4];
  #pragma unroll
  for (int p=0;p<4;p++){
    const int g = p*256 + t;
    ksrc[p] = ((size_t)((b<<11) + (g>>4))*16 + h)*128 + (size_t)((((g&15) ^ ((g>>4)&7))*8));
    vsrc[p] = ((size_t)(b*16 + h)*128 + (g>>3))*2048 + (size_t)((((g&7) ^ ((g>>3)&7))*8));
  }

#define STK(T, DB) { const size_t ko_ = (size_t)(T)*131072; \
    _Pragma("unroll") for (int p_=0;p_<4;p_++) gll16(Kh_ + ksrc[p_] + ko_, &Ksh[DB][0] + (p_*256+t)*8); }
#define STV(T) { const int vo_ = (T)*64; \
    _Pragma("unroll") for (int p_=0;p_<4;p_++) gll16(Vt + vsrc[p_] + vo_, &Vsh[0] + (p_*256+t)*8); }

  // prologue: K0, V0, K1 in flight (12 loads); wait K0+V0 (leave K1's 4)
  STK(0,0); STV(0); STK(1,1);
  asm volatile("s_waitcnt vmcnt(4)" ::: "memory");
  __builtin_amdgcn_s_barrier();

  for (int tt = 0; tt < 32; ++tt){
    const int c = tt & 1;

    // QK^T from Ksh[c] (K[tt] resident; K[tt+1] + possibly V[tt] in flight)
    f32x4 sa[2][4] = {};
    #pragma unroll
    for (int ks=0;ks<4;ks++){
      const int row = ks*16 + l15;
      #pragma unroll
      for (int kk=0;kk<4;kk++){
        const int off = row*128 + (((kk*4 + l4) ^ (row&7))*8);
        f16x8 khf = *(const f16x8*)&Ksh[c][off];
        sa[0][ks] = MFMAH(qh[0][kk], khf, sa[0][ks]);
        sa[1][ks] = MFMAH(qh[1][kk], khf, sa[1][ks]);
      }
    }
    // static-offset softmax: P = exp(s - 24)
    #pragma unroll
    for (int qf=0;qf<2;qf++)
      #pragma unroll
      for (int r=0;r<4;r++){
        float rs = 0.f;
        #pragma unroll
        for (int ks=0;ks<4;ks++){
          const float e = __expf(sa[qf][ks][r] - 24.f);
          rs += e;
          Psh[w][(qf*16 + l4*4 + r)*72 + ks*16 + l15] = f2bf(e);
        }
        lpart[qf][r] += rs;
      }
    // V[tt] done (leave K[tt+1]'s 4 in flight); P writes flushed
    asm volatile("s_waitcnt vmcnt(4) lgkmcnt(0)" ::: "memory");
    __builtin_amdgcn_sched_barrier(0);
    __builtin_amdgcn_s_barrier();          // V[tt] visible to all waves

    // PV from Vsh
    #pragma unroll
    for (int ks2=0;ks2<2;ks2++){
      bf16x8 pa0 = *(const bf16x8*)&Psh[w][(l15)*72 + ks2*32 + l4*8];
      bf16x8 pa1 = *(const bf16x8*)&Psh[w][(16 + l15)*72 + ks2*32 + l4*8];
      #pragma unroll
      for (int n=0;n<8;n++){
        const int row = n*16 + l15;
        const int c8 = ks2*4 + l4;
        bf16x8 vb = *(const bf16x8*)&Vsh[row*64 + ((c8 ^ (row&7))*8)];
        oacc[0][n] = MFMA16(pa0, vb, oacc[0][n]);
        oacc[1][n] = MFMA16(pa1, vb, oacc[1][n]);
      }
    }
    __builtin_amdgcn_s_barrier();          // Vsh and Ksh[c] free

    // restage: V[tt+1] over Vsh, K[tt+2] over Ksh[c] (clamped dummies at tail)
    const int tv = (tt+1 < 32) ? tt+1 : 31;
    const int tk = (tt+2 < 32) ? tt+2 : 31;
    STV(tv); STK(tk, c);
    asm volatile("s_waitcnt vmcnt(8)" ::: "memory");   // K[tt+1] done
    __builtin_amdgcn_s_barrier();          // K[tt+1] visible for next QK
  }
  asm volatile("s_waitcnt vmcnt(0)" ::: "memory");     // drain tail dummies

#undef STK
#undef STV

  #pragma unroll
  for (int qf=0;qf<2;qf++){
    float lrun[4];
    #pragma unroll
    for (int r=0;r<4;r++){
      float s = lpart[qf][r];
      #pragma unroll
      for (int d=1; d<16; d<<=1) s += __shfl_xor(s, d, 64);
      lrun[r] = s;
    }
    #pragma unroll
    for (int n=0;n<8;n++){
      const int d = n*16 + l15;
      #pragma unroll
      for (int r=0;r<4;r++){
        const int s = q0 + qf*16 + l4*4 + r;
        f16 hv = (f16)(oacc[qf][n][r] / lrun[r]);
        O[((size_t)((b<<11) + s)*16 + h)*128 + d] = *reinterpret_cast<u16*>(&hv);
      }
    }
  }
}

extern "C" void kernel_launch(void* const* d_in, const int* in_sizes, int n_in,
                              void* d_out, int out_size, void* d_ws, size_t ws_size,
                              hipStream_t stream){
  const float* f_inq = (const float*)d_in[0];
  const float* f_inkv= (const float*)d_in[1];
  const float* f_Wq  = (const float*)d_in[2];
  const float* f_Wk  = (const float*)d_in[3];
  const float* f_Wv  = (const float*)d_in[4];
  const float* scq   = (const float*)d_in[5];
  const float* sck   = (const float*)d_in[6];
  const float* f_Wo  = (const float*)d_in[7];

  u16* ws = (u16*)d_ws;
  const size_t ACT = (size_t)16777216;   // 4*2048*16*128
  const size_t WEL = (size_t)4194304;    // 2048*2048
  u16* q_h = ws;               // fp16
  u16* k_h = q_h + ACT;        // fp16
  u16* v_t = k_h + ACT;        // bf16 [B,H,Dh,S]
  u16* ctx = v_t + ACT;        // fp16
  u16* wq  = ctx + ACT;        // fp16 weights, x256
  u16* wk  = wq + WEL;
  u16* wv  = wk + WEL;
  u16* wo  = wv + WEL;

  u16* inq16  = (u16*)d_out;   // fp16 input staging in d_out, consumed before final GEMM
  u16* inkv16 = inq16 + ACT;

  prep<<<20480, 256, 0, stream>>>(f_inq, f_inkv, inq16, inkv16,
                                  f_Wq, f_Wk, f_Wv, f_Wo, wq, wk, wv, wo);

  gemm8_qkv<<<768, 512, 0, stream>>>(inq16, inkv16, wq, wk, wv, scq, sck, q_h, k_h, v_t);

  attn_fwd<<<dim3(1024), 256, 0, stream>>>(q_h, k_h, v_t, ctx);

  gemm8_out<<<256, 512, 0, stream>>>(ctx, wo, (float*)d_out);
}

// Round 16
// 505.168 us; speedup vs baseline: 1.2230x; 1.0138x over previous
//
#include <hip/hip_runtime.h>
#include <hip/hip_bf16.h>

typedef unsigned short u16;
typedef unsigned int u32;
typedef _Float16 f16;
typedef __attribute__((ext_vector_type(8))) short bf16x8;
typedef __attribute__((ext_vector_type(8))) _Float16 f16x8;
typedef __attribute__((ext_vector_type(4))) float f32x4;
typedef __attribute__((ext_vector_type(4))) u16 u16x4;

__device__ __forceinline__ float bf2f(u16 u){ return __uint_as_float(((u32)u) << 16); }
__device__ __forceinline__ u16 f2bf(float f){
  u32 u = __float_as_uint(f);
  u += 0x7fffu + ((u >> 16) & 1u);
  return (u16)(u >> 16);
}
__device__ __forceinline__ void gll16(const u16* g, u16* l){
  __builtin_amdgcn_global_load_lds((const __attribute__((address_space(1))) u32*)g,
                                   (__attribute__((address_space(3))) u32*)l, 16, 0, 0);
}

#define MFMA16(a,b,c) __builtin_amdgcn_mfma_f32_16x16x32_bf16((a),(b),(c),0,0,0)
#define MFMAH(a,b,c)  __builtin_amdgcn_mfma_f32_16x16x32_f16((a),(b),(c),0,0,0)

// ---------------- merged preprocessing: fp32->fp16 inputs + 4x weight transpose (x256) ----------------
__global__ __launch_bounds__(256) void prep(const float* __restrict__ inq, const float* __restrict__ inkv,
                                            u16* __restrict__ oq, u16* __restrict__ okv,
                                            const float* __restrict__ w0, const float* __restrict__ w1,
                                            const float* __restrict__ w2, const float* __restrict__ w3,
                                            u16* __restrict__ o0, u16* __restrict__ o1,
                                            u16* __restrict__ o2, u16* __restrict__ o3){
  __shared__ float tile[64*68];
  const int bid = blockIdx.x;
  const int t = threadIdx.x;
  if (bid < 16384){
    const int half = bid >> 13;
    const float* in = half ? inkv : inq;
    u16* out = half ? okv : oq;
    const size_t i = ((size_t)(bid & 8191)*256 + t)*8;
    f16 h[8];
    #pragma unroll
    for (int j=0;j<8;j++) h[j] = (f16)in[i+j];
    *(f16x8*)(out+i) = *(f16x8*)h;
    return;
  }
  const int r = bid - 16384;
  const int z = r >> 10, b2 = r & 1023;
  const float* in = (z==0) ? w0 : (z==1) ? w1 : (z==2) ? w2 : w3;
  u16* oh = (z==0) ? o0 : (z==1) ? o1 : (z==2) ? o2 : o3;
  const int r0 = (b2 >> 5)*64, c0 = (b2 & 31)*64;
  #pragma unroll
  for (int p=0;p<2;p++){
    const int row = p*32 + (t>>3), cg = (t&7)*8;
    const float* s = in + (size_t)(r0+row)*2048 + c0 + cg;
    #pragma unroll
    for (int j=0;j<8;j++) tile[row*68 + cg + j] = s[j];
  }
  __syncthreads();
  #pragma unroll
  for (int p=0;p<2;p++){
    const int orow = p*32 + (t>>3), cg = (t&7)*8;
    f16 h[8];
    #pragma unroll
    for (int j=0;j<8;j++) h[j] = (f16)(tile[(cg+j)*68 + orow] * 256.f);
    *(f16x8*)(oh + (size_t)(c0+orow)*2048 + r0 + cg) = *(f16x8*)h;
  }
}

// ============ 2-phase-per-K-tile 256x256 fp16 GEMM main loop (32 MFMA clusters) ============
// Phase A: all 8 A-frags + 4 B-frags of khalf0, stage t1-kh1 -> db1, 32 MFMA.
// Phase B: khalf1, stage t2-kh0 over freed kh0 region, 32 MFMA, counted vmcnt(4).
// Lifetimes identical to the 4-phase schedule; barriers per K-tile halved 8->4.
#define STG_A(tile, kh, db) { const u16* s_ = gA + (size_t)(tile)*64 + (kh)*32; \
    gll16(s_, &AL[db][kh][0] + d0); gll16(s_ + (size_t)128*2048, &AL[db][kh][0] + d1); }
#define STG_B(tile, kh, db) { const u16* s_ = gB + (size_t)(tile)*64 + (kh)*32; \
    gll16(s_, &AL[2+db][kh][0] + d0); gll16(s_ + (size_t)128*2048, &AL[2+db][kh][0] + d1); }

#define GEMM8_MAIN_LOOP(A_, B_)                                                     \
  const int srow = t >> 2;                                                          \
  const int skg = (t & 3) ^ ((srow ^ (srow >> 2)) & 3);                             \
  const u16* gA = A_ + (size_t)(m0 + srow) * 2048 + skg * 8;                        \
  const u16* gB = B_ + (size_t)(n0 + srow) * 2048 + skg * 8;                        \
  const int d0 = (w * 64) * 8;                                                      \
  const int d1 = (512 + w * 64) * 8;                                                \
  const int sz = (l15 ^ (l15 >> 2)) & 3;                                            \
  const int kgp = ((l4 ^ sz) & 3) * 8;                                              \
  const int aoff = (wm * 128 + l15) * 32 + kgp;                                     \
  const int boff = (wn * 64 + l15) * 32 + kgp;                                      \
  STG_A(0,0,0); STG_B(0,0,0);                                                       \
  STG_A(0,1,0); STG_B(0,1,0);                                                       \
  STG_A(1,0,1); STG_B(1,0,1);                                                       \
  asm volatile("s_waitcnt vmcnt(4)" ::: "memory");                                  \
  __builtin_amdgcn_s_barrier();                                                     \
  for (int g = 0; g < 32; ++g){                                                     \
    const int db = g & 1, db1 = db ^ 1;                                             \
    const int t1 = (g+1 < 32) ? g+1 : 31;                                           \
    const int t2 = (g+2 < 32) ? g+2 : 31;                                           \
    f16x8 a[8], b[4];                                                               \
    /* phase A: khalf0 */                                                           \
    _Pragma("unroll")                                                               \
    for (int nf=0; nf<4; nf++) b[nf] = *(const f16x8*)&AL[2+db][0][boff + nf*512];  \
    _Pragma("unroll")                                                               \
    for (int mf=0; mf<8; mf++) a[mf] = *(const f16x8*)&AL[db][0][aoff + mf*512];    \
    STG_A(t1, 1, db1); STG_B(t1, 1, db1);                                           \
    __builtin_amdgcn_s_barrier();                                                   \
    asm volatile("s_waitcnt lgkmcnt(0)" ::: "memory");                              \
    __builtin_amdgcn_sched_barrier(0);                                              \
    __builtin_amdgcn_s_setprio(1);                                                  \
    _Pragma("unroll")                                                               \
    for (int mf=0; mf<8; mf++)                                                      \
      _Pragma("unroll")                                                             \
      for (int nf=0; nf<4; nf++)                                                    \
        acc[mf][nf] = MFMAH(a[mf], b[nf], acc[mf][nf]);                             \
    __builtin_amdgcn_s_setprio(0);                                                  \
    __builtin_amdgcn_s_barrier();                                                   \
    /* phase B: khalf1 */                                                           \
    _Pragma("unroll")                                                               \
    for (int nf=0; nf<4; nf++) b[nf] = *(const f16x8*)&AL[2+db][1][boff + nf*512];  \
    _Pragma("unroll")                                                               \
    for (int mf=0; mf<8; mf++) a[mf] = *(const f16x8*)&AL[db][1][aoff + mf*512];    \
    STG_A(t2, 0, db); STG_B(t2, 0, db);                                             \
    __builtin_amdgcn_s_barrier();                                                   \
    asm volatile("s_waitcnt lgkmcnt(0)" ::: "memory");                              \
    __builtin_amdgcn_sched_barrier(0);                                              \
    __builtin_amdgcn_s_setprio(1);                                                  \
    _Pragma("unroll")                                                               \
    for (int mf=0; mf<8; mf++)                                                      \
      _Pragma("unroll")                                                             \
      for (int nf=0; nf<4; nf++)                                                    \
        acc[mf][nf] = MFMAH(a[mf], b[nf], acc[mf][nf]);                             \
    __builtin_amdgcn_s_setprio(0);                                                  \
    asm volatile("s_waitcnt vmcnt(4)" ::: "memory");                                \
    __builtin_amdgcn_s_barrier();                                                   \
  }                                                                                 \
  asm volatile("s_waitcnt vmcnt(0)" ::: "memory");                                  \
  __builtin_amdgcn_s_barrier();

// -------- fused q/k/v projection GEMMs: z selects operands; epilogue RMSNorm(fp16) or V-transpose(bf16) --------
__global__ __launch_bounds__(512, 1) void gemm8_qkv(const u16* __restrict__ inq, const u16* __restrict__ inkv,
                                                    const u16* __restrict__ wq, const u16* __restrict__ wk,
                                                    const u16* __restrict__ wv,
                                                    const float* __restrict__ scq, const float* __restrict__ sck,
                                                    u16* __restrict__ q_h, u16* __restrict__ k_h,
                                                    u16* __restrict__ v_t){
  __shared__ __align__(16) u16 AL[4][2][8192];   // [0,1]=A dbuf, [2,3]=B dbuf
  __shared__ float red[2][4][128];

  const int t = threadIdx.x;
  const int lane = t & 63, w = t >> 6;
  const int wm = w >> 2, wn = w & 3;
  const int l15 = lane & 15, l4 = lane >> 4;

  const int z = blockIdx.x >> 8;
  const int bid = blockIdx.x & 255;
  const int xcd = bid & 7, q = bid >> 3;
  const int m0 = (((xcd >> 1) << 3) + (q >> 2)) * 256;
  const int n0 = (((xcd & 1) << 2) + (q & 3)) * 256;

  const u16* A  = (z==0) ? inq : inkv;
  const u16* Bt = (z==0) ? wq : (z==1) ? wk : wv;
  const float* scale = (z==0) ? scq : sck;

  f32x4 acc[8][4] = {};
  GEMM8_MAIN_LOOP(A, Bt)

  const float us = 1.f/256.f;
  if (z < 2){
    u16* C = (z==0) ? q_h : k_h;
    #pragma unroll
    for (int mf=0; mf<8; mf++)
      #pragma unroll
      for (int nf=0; nf<4; nf++)
        #pragma unroll
        for (int r=0;r<4;r++) acc[mf][nf][r] *= us;
    #pragma unroll
    for (int mf=0; mf<8; mf++){
      #pragma unroll
      for (int r=0;r<4;r++){
        float p = acc[mf][0][r]*acc[mf][0][r] + acc[mf][1][r]*acc[mf][1][r]
                + acc[mf][2][r]*acc[mf][2][r] + acc[mf][3][r]*acc[mf][3][r];
        #pragma unroll
        for (int d=1; d<16; d<<=1) p += __shfl_xor(p, d, 64);
        if (l15 == 0) red[wm][wn][mf*16 + l4*4 + r] = p;
      }
    }
    __syncthreads();
    float sc[4];
    #pragma unroll
    for (int nf=0; nf<4; nf++) sc[nf] = scale[(wn*64 + nf*16 + l15) & 127];
    #pragma unroll
    for (int mf=0; mf<8; mf++){
      #pragma unroll
      for (int r=0;r<4;r++){
        const int rl = mf*16 + l4*4 + r;
        const float inv = rsqrtf((red[wm][wn & 2][rl] + red[wm][(wn & 2) | 1][rl])*(1.f/128.f) + 1e-6f);
        const size_t grow = (size_t)(m0 + wm*128 + rl);
        #pragma unroll
        for (int nf=0; nf<4; nf++){
          f16 hv = (f16)(acc[mf][nf][r]*inv*sc[nf]);
          C[grow*2048 + (n0 + wn*64 + nf*16 + l15)] = *reinterpret_cast<u16*>(&hv);
        }
      }
    }
  } else {
    #pragma unroll
    for (int mf=0; mf<8; mf++){
      const int m = m0 + wm*128 + mf*16 + l4*4;
      const int bb = m >> 11, s = m & 2047;
      #pragma unroll
      for (int nf=0; nf<4; nf++){
        const int n = n0 + wn*64 + nf*16 + l15;
        u16x4 pk;
        pk.x = f2bf(acc[mf][nf][0]*us); pk.y = f2bf(acc[mf][nf][1]*us);
        pk.z = f2bf(acc[mf][nf][2]*us); pk.w = f2bf(acc[mf][nf][3]*us);
        *(u16x4*)&v_t[((size_t)(bb*16 + (n>>7))*128 + (n&127))*2048 + s] = pk;
      }
    }
  }
}

// -------- final GEMM: ctx x Wo -> fp32 out --------
__global__ __launch_bounds__(512, 1) void gemm8_out(const u16* __restrict__ A,
                                                    const u16* __restrict__ Bt,
                                                    float* __restrict__ Cf){
  __shared__ __align__(16) u16 AL[4][2][8192];
  const int t = threadIdx.x;
  const int lane = t & 63, w = t >> 6;
  const int wm = w >> 2, wn = w & 3;
  const int l15 = lane & 15, l4 = lane >> 4;

  const int bid = blockIdx.x;
  const int xcd = bid & 7, q = bid >> 3;
  const int m0 = (((xcd >> 1) << 3) + (q >> 2)) * 256;
  const int n0 = (((xcd & 1) << 2) + (q & 3)) * 256;

  f32x4 acc[8][4] = {};
  GEMM8_MAIN_LOOP(A, Bt)

  const float us = 1.f/256.f;
  #pragma unroll
  for (int mf=0; mf<8; mf++){
    const size_t r0 = (size_t)(m0 + wm*128 + mf*16 + l4*4);
    #pragma unroll
    for (int nf=0; nf<4; nf++){
      const int c = n0 + wn*64 + nf*16 + l15;
      #pragma unroll
      for (int r=0;r<4;r++)
        Cf[(r0+r)*2048 + c] = acc[mf][nf][r]*us;
    }
  }
}

// ---------------- Flash attention: counted-vmcnt pipeline (r11 verbatim, 190us verified) ----------------
__global__ __launch_bounds__(256, 2) void attn_fwd(const u16* __restrict__ Qh_,
                                                   const u16* __restrict__ Kh_,
                                                   const u16* __restrict__ Vt, u16* __restrict__ O){
  __shared__ __align__(16) u16 Ksh[2][64*128];   // fp16 dbuf, granule-swizzled content
  __shared__ __align__(16) u16 Vsh[128*64];      // bf16 single buffer
  __shared__ __align__(16) u16 Psh[4][32*72];    // bf16 per-wave P
  const int t = threadIdx.x;
  const int lane = t & 63, w = t >> 6;
  const int l15 = lane & 15, l4 = lane >> 4;
  const int lin = blockIdx.x;
  const int bh  = (lin & 7)*8 + (lin >> 7);
  const int qt  = (lin >> 3) & 15;
  const int b = bh >> 4, h = bh & 15;
  const int q0 = qt*128 + w*32;

  f16x8 qh[2][4];
  #pragma unroll
  for (int qf=0;qf<2;qf++){
    const size_t qoff = ((size_t)((b<<11) + q0 + qf*16 + l15)*16 + h)*128 + l4*8;
    #pragma unroll
    for (int kk=0;kk<4;kk++)
      qh[qf][kk] = *(const f16x8*)(Qh_ + qoff + kk*32);
  }
  f32x4 oacc[2][8] = {};
  float lpart[2][4] = {};

  size_t ksrc[4], vsrc[4];
  #pragma unroll
  for (int p=0;p<4;p++){
    const int g = p*256 + t;
    ksrc[p] = ((size_t)((b<<11) + (g>>4))*16 + h)*128 + (size_t)((((g&15) ^ ((g>>4)&7))*8));
    vsrc[p] = ((size_t)(b*16 + h)*128 + (g>>3))*2048 + (size_t)((((g&7) ^ ((g>>3)&7))*8));
  }

#define STK(T, DB) { const size_t ko_ = (size_t)(T)*131072; \
    _Pragma("unroll") for (int p_=0;p_<4;p_++) gll16(Kh_ + ksrc[p_] + ko_, &Ksh[DB][0] + (p_*256+t)*8); }
#define STV(T) { const int vo_ = (T)*64; \
    _Pragma("unroll") for (int p_=0;p_<4;p_++) gll16(Vt + vsrc[p_] + vo_, &Vsh[0] + (p_*256+t)*8); }

  // prologue: K0, V0, K1 in flight (12 loads); wait K0+V0 (leave K1's 4)
  STK(0,0); STV(0); STK(1,1);
  asm volatile("s_waitcnt vmcnt(4)" ::: "memory");
  __builtin_amdgcn_s_barrier();

  for (int tt = 0; tt < 32; ++tt){
    const int c = tt & 1;

    // QK^T from Ksh[c] (K[tt] resident; K[tt+1] + possibly V[tt] in flight)
    f32x4 sa[2][4] = {};
    #pragma unroll
    for (int ks=0;ks<4;ks++){
      const int row = ks*16 + l15;
      #pragma unroll
      for (int kk=0;kk<4;kk++){
        const int off = row*128 + (((kk*4 + l4) ^ (row&7))*8);
        f16x8 khf = *(const f16x8*)&Ksh[c][off];
        sa[0][ks] = MFMAH(qh[0][kk], khf, sa[0][ks]);
        sa[1][ks] = MFMAH(qh[1][kk], khf, sa[1][ks]);
      }
    }
    // static-offset softmax: P = exp(s - 24)
    #pragma unroll
    for (int qf=0;qf<2;qf++)
      #pragma unroll
      for (int r=0;r<4;r++){
        float rs = 0.f;
        #pragma unroll
        for (int ks=0;ks<4;ks++){
          const float e = __expf(sa[qf][ks][r] - 24.f);
          rs += e;
          Psh[w][(qf*16 + l4*4 + r)*72 + ks*16 + l15] = f2bf(e);
        }
        lpart[qf][r] += rs;
      }
    // V[tt] done (leave K[tt+1]'s 4 in flight); P writes flushed
    asm volatile("s_waitcnt vmcnt(4) lgkmcnt(0)" ::: "memory");
    __builtin_amdgcn_sched_barrier(0);
    __builtin_amdgcn_s_barrier();          // V[tt] visible to all waves

    // PV from Vsh
    #pragma unroll
    for (int ks2=0;ks2<2;ks2++){
      bf16x8 pa0 = *(const bf16x8*)&Psh[w][(l15)*72 + ks2*32 + l4*8];
      bf16x8 pa1 = *(const bf16x8*)&Psh[w][(16 + l15)*72 + ks2*32 + l4*8];
      #pragma unroll
      for (int n=0;n<8;n++){
        const int row = n*16 + l15;
        const int c8 = ks2*4 + l4;
        bf16x8 vb = *(const bf16x8*)&Vsh[row*64 + ((c8 ^ (row&7))*8)];
        oacc[0][n] = MFMA16(pa0, vb, oacc[0][n]);
        oacc[1][n] = MFMA16(pa1, vb, oacc[1][n]);
      }
    }
    __builtin_amdgcn_s_barrier();          // Vsh and Ksh[c] free

    // restage: V[tt+1] over Vsh, K[tt+2] over Ksh[c] (clamped dummies at tail)
    const int tv = (tt+1 < 32) ? tt+1 : 31;
    const int tk = (tt+2 < 32) ? tt+2 : 31;
    STV(tv); STK(tk, c);
    asm volatile("s_waitcnt vmcnt(8)" ::: "memory");   // K[tt+1] done
    __builtin_amdgcn_s_barrier();          // K[tt+1] visible for next QK
  }
  asm volatile("s_waitcnt vmcnt(0)" ::: "memory");     // drain tail dummies

#undef STK
#undef STV

  #pragma unroll
  for (int qf=0;qf<2;qf++){
    float lrun[4];
    #pragma unroll
    for (int r=0;r<4;r++){
      float s = lpart[qf][r];
      #pragma unroll
      for (int d=1; d<16; d<<=1) s += __shfl_xor(s, d, 64);
      lrun[r] = s;
    }
    #pragma unroll
    for (int n=0;n<8;n++){
      const int d = n*16 + l15;
      #pragma unroll
      for (int r=0;r<4;r++){
        const int s = q0 + qf*16 + l4*4 + r;
        f16 hv = (f16)(oacc[qf][n][r] / lrun[r]);
        O[((size_t)((b<<11) + s)*16 + h)*128 + d] = *reinterpret_cast<u16*>(&hv);
      }
    }
  }
}

extern "C" void kernel_launch(void* const* d_in, const int* in_sizes, int n_in,
                              void* d_out, int out_size, void* d_ws, size_t ws_size,
                              hipStream_t stream){
  const float* f_inq = (const float*)d_in[0];
  const float* f_inkv= (const float*)d_in[1];
  const float* f_Wq  = (const float*)d_in[2];
  const float* f_Wk  = (const float*)d_in[3];
  const float* f_Wv  = (const float*)d_in[4];
  const float* scq   = (const float*)d_in[5];
  const float* sck   = (const float*)d_in[6];
  const float* f_Wo  = (const float*)d_in[7];

  u16* ws = (u16*)d_ws;
  const size_t ACT = (size_t)16777216;   // 4*2048*16*128
  const size_t WEL = (size_t)4194304;    // 2048*2048
  u16* q_h = ws;               // fp16
  u16* k_h = q_h + ACT;        // fp16
  u16* v_t = k_h + ACT;        // bf16 [B,H,Dh,S]
  u16* ctx = v_t + ACT;        // fp16
  u16* wq  = ctx + ACT;        // fp16 weights, x256
  u16* wk  = wq + WEL;
  u16* wv  = wk + WEL;
  u16* wo  = wv + WEL;

  u16* inq16  = (u16*)d_out;   // fp16 input staging in d_out, consumed before final GEMM
  u16* inkv16 = inq16 + ACT;

  prep<<<20480, 256, 0, stream>>>(f_inq, f_inkv, inq16, inkv16,
                                  f_Wq, f_Wk, f_Wv, f_Wo, wq, wk, wv, wo);

  gemm8_qkv<<<768, 512, 0, stream>>>(inq16, inkv16, wq, wk, wv, scq, sck, q_h, k_h, v_t);

  attn_fwd<<<dim3(1024), 256, 0, stream>>>(q_h, k_h, v_t, ctx);

  gemm8_out<<<256, 512, 0, stream>>>(ctx, wo, (float*)d_out);
}